// Round 1
// baseline (164.642 us; speedup 1.0000x reference)
//
#include <hip/hip_runtime.h>
#include <math.h>

#define BB 16
#define TT 4096
#define EE 1024
#define HALF 2048
#define WIN 15
#define EPSF 1e-6f
#define PI_F 3.14159265358979323846f

// ---------------------------------------------------------------------------
// Kernel 1: phases + c0, one wave (64 lanes) per (b,t) row of E=1024 floats.
// Writes transposed layouts phases_T[t*16+b], c0_T[t*16+b] so the GEMV stage
// can read all 16 batch values as 4x float4.
// ---------------------------------------------------------------------------
__global__ void phase_kernel(const float* __restrict__ x,
                             const float* __restrict__ taper,
                             float* __restrict__ phases_T,
                             float* __restrict__ c0_T) {
    const int wave = threadIdx.x >> 6;
    const int lane = threadIdx.x & 63;
    const int row  = blockIdx.x * 4 + wave;      // [0, B*T)
    const int b = row >> 12;                     // row / T
    const int t = row & (TT - 1);                // row % T
    const float tap = taper[t];
    const float* xr = x + (size_t)row * EE;

    const float x0 = xr[0];                      // broadcast load (one line)
    const float c0 = x0 * tap;
    const float r = fabsf(c0) + EPSF;
    const float inv_r = 1.0f / r;
    const float start = (c0 >= 0.0f) ? 0.0f : PI_F;

    const float LO = -1.0f + EPSF;
    const float HI =  1.0f - EPSF;

    const float4* xr4 = (const float4*)xr;       // 256 float4 per row
    float sum = 0.0f;
    #pragma unroll
    for (int j = 0; j < 4; ++j) {
        float4 v = xr4[j * 64 + lane];           // coalesced 1 KiB / instr
        const int e0 = (j * 64 + lane) * 4;
        float a;
        if (e0 != 0) {                           // skip element 0 (c0)
            a = fminf(fmaxf(v.x * tap * inv_r, LO), HI);
            sum += asinf(a);
        }
        a = fminf(fmaxf(v.y * tap * inv_r, LO), HI); sum += asinf(a);
        a = fminf(fmaxf(v.z * tap * inv_r, LO), HI); sum += asinf(a);
        a = fminf(fmaxf(v.w * tap * inv_r, LO), HI); sum += asinf(a);
    }
    // wave-64 butterfly reduce
    #pragma unroll
    for (int off = 32; off > 0; off >>= 1)
        sum += __shfl_xor(sum, off, 64);

    if (lane == 0) {
        phases_T[t * BB + b] = start + sum;
        c0_T[t * BB + b]     = c0;
    }
}

// ---------------------------------------------------------------------------
// Kernel 2: causal triangular moving average over previous WIN steps.
// tdiff[t] = (sum_{d=1..min(t,WIN)} d * c0[t-d]) / (s(s+1)/2)
// ---------------------------------------------------------------------------
__global__ void tdiff_kernel(const float* __restrict__ c0_T,
                             float* __restrict__ tdiff_T) {
    const int f = blockIdx.x * blockDim.x + threadIdx.x;   // t*16 + b
    if (f >= BB * TT) return;
    const int t = f >> 4;
    const int b = f & 15;
    float num = 0.0f;
    #pragma unroll
    for (int d = 1; d <= WIN; ++d) {
        if (d <= t) num += (float)d * c0_T[(t - d) * BB + b];
    }
    const int s = (t < WIN) ? t : WIN;
    const float norm = 0.5f * (float)s * (float)(s + 1);
    tdiff_T[f] = (norm > 0.0f) ? (num / norm) : 0.0f;
}

// ---------------------------------------------------------------------------
// Skinny GEMM (M=16): C[b,o] = act( sum_k A_T[k,b] * W[o,k] + bias[o] ).
// A stored transposed (k-major, 16 floats per k). 8 output cols per block,
// 32 threads per col striding k, f32 accumulate, deterministic LDS reduce.
// Two independent problems (c-path, p-path) fused in one grid.
// MODE 0: silu -> H_T[o*16+b].   MODE 1: tanh -> out[b*4096 + o*2 + g].
// ---------------------------------------------------------------------------
template <int K, int MODE>
__global__ void gemm_kernel(const float* __restrict__ A0,
                            const float* __restrict__ W0,
                            const float* __restrict__ bias0,
                            float* __restrict__ out0,
                            const float* __restrict__ A1,
                            const float* __restrict__ W1,
                            const float* __restrict__ bias1,
                            float* __restrict__ out1) {
    const int BO = 8;
    const int nb = HALF / BO;                 // 256 blocks per problem
    const int g = blockIdx.x / nb;            // which compressor
    const int obase = (blockIdx.x % nb) * BO;

    const float* A    = g ? A1 : A0;
    const float* W    = g ? W1 : W0;
    const float* bias = g ? bias1 : bias0;
    float* out        = g ? out1 : out0;

    const int og = threadIdx.x >> 5;          // 0..7 output col in block
    const int ln = threadIdx.x & 31;          // k-stripe
    const int o = obase + og;
    const float* wrow = W + (size_t)o * K;
    const float4* A4 = (const float4*)A;

    float acc[16];
    #pragma unroll
    for (int i = 0; i < 16; ++i) acc[i] = 0.0f;

    #pragma unroll 4
    for (int k = ln; k < K; k += 32) {
        const float w = wrow[k];
        float4 a0 = A4[k * 4 + 0];
        float4 a1 = A4[k * 4 + 1];
        float4 a2 = A4[k * 4 + 2];
        float4 a3 = A4[k * 4 + 3];
        acc[0]  += w * a0.x; acc[1]  += w * a0.y; acc[2]  += w * a0.z; acc[3]  += w * a0.w;
        acc[4]  += w * a1.x; acc[5]  += w * a1.y; acc[6]  += w * a1.z; acc[7]  += w * a1.w;
        acc[8]  += w * a2.x; acc[9]  += w * a2.y; acc[10] += w * a2.z; acc[11] += w * a2.w;
        acc[12] += w * a3.x; acc[13] += w * a3.y; acc[14] += w * a3.z; acc[15] += w * a3.w;
    }

    __shared__ float red[8][32][16];          // 16 KiB
    #pragma unroll
    for (int i = 0; i < 16; ++i) red[og][ln][i] = acc[i];
    __syncthreads();

    if (threadIdx.x < 128) {
        const int o2 = threadIdx.x >> 4;      // 0..7
        const int b  = threadIdx.x & 15;      // 0..15
        float s = 0.0f;
        #pragma unroll
        for (int j = 0; j < 32; ++j) s += red[o2][j][b];
        s += bias[obase + o2];
        if (MODE == 0) {
            s = s / (1.0f + expf(-s));        // silu
            out[(obase + o2) * BB + b] = s;
        } else {
            s = tanhf(s);
            out[(size_t)b * (HALF * 2) + (obase + o2) * 2 + g] = s;
        }
    }
}

extern "C" void kernel_launch(void* const* d_in, const int* in_sizes, int n_in,
                              void* d_out, int out_size, void* d_ws, size_t ws_size,
                              hipStream_t stream) {
    const float* x     = (const float*)d_in[0];
    const float* taper = (const float*)d_in[1];
    const float* cW1   = (const float*)d_in[2];
    const float* cb1   = (const float*)d_in[3];
    const float* cW2   = (const float*)d_in[4];
    const float* cb2   = (const float*)d_in[5];
    const float* pW1   = (const float*)d_in[6];
    const float* pb1   = (const float*)d_in[7];
    const float* pW2   = (const float*)d_in[8];
    const float* pb2   = (const float*)d_in[9];
    float* out = (float*)d_out;
    float* ws  = (float*)d_ws;

    float* phases_T = ws;                         // 65536
    float* c0_T     = ws + 65536;                 // 65536
    float* tdiff_T  = ws + 131072;                // 65536
    float* H1_T     = ws + 196608;                // 32768
    float* H2_T     = ws + 229376;                // 32768

    phase_kernel<<<BB * TT / 4, 256, 0, stream>>>(x, taper, phases_T, c0_T);
    tdiff_kernel<<<BB * TT / 256, 256, 0, stream>>>(c0_T, tdiff_T);
    gemm_kernel<TT, 0><<<512, 256, 0, stream>>>(phases_T, cW1, cb1, H1_T,
                                                tdiff_T, pW1, pb1, H2_T);
    gemm_kernel<HALF, 1><<<512, 256, 0, stream>>>(H1_T, cW2, cb2, out,
                                                  H2_T, pW2, pb2, out);
}